// Round 3
// baseline (279.264 us; speedup 1.0000x reference)
//
#include <hip/hip_runtime.h>

// loss = sum((input - target)^2) / (N/4), by orthonormality of the 2x2 Haar
// transform (sum of the 4 band MSEs == overall pixel SSE * 4/N).
// N = 4*32*512*512 = 33554432; divisor = N/4 = 8388608.
//
// Stage 1: each block reduces a CONTIGUOUS chunk of 4096 float4s per tensor
//          (better DRAM row locality than grid-stride) and stores its partial
//          to ws[blockIdx] with a plain store (no atomics -> no serialized
//          same-address RMW tail when all blocks finish simultaneously).
// Stage 2: one block sums the 2048 partials and writes the scaled scalar.

#define S1_BLOCK 256
#define S1_ITERS 16                      // float4s per thread per tensor
#define S1_CHUNK (S1_BLOCK * S1_ITERS)   // 4096 float4s per block

__global__ __launch_bounds__(S1_BLOCK) void haar_mse_stage1(
    const float4* __restrict__ x,
    const float4* __restrict__ t,
    float* __restrict__ ws,
    int n4)
{
    const int tid  = threadIdx.x;
    const int base = blockIdx.x * S1_CHUNK + tid;

    float acc0 = 0.0f, acc1 = 0.0f, acc2 = 0.0f, acc3 = 0.0f;

    if (base + (S1_ITERS - 1) * S1_BLOCK < n4) {
        // fast path: whole chunk in bounds (always true for the bench shape)
        #pragma unroll
        for (int g = 0; g < S1_ITERS / 4; ++g) {
            const int i0 = base + (g * 4 + 0) * S1_BLOCK;
            const int i1 = base + (g * 4 + 1) * S1_BLOCK;
            const int i2 = base + (g * 4 + 2) * S1_BLOCK;
            const int i3 = base + (g * 4 + 3) * S1_BLOCK;
            // batch 8 independent loads (contiguous 1KB wave-lines)
            float4 a0 = x[i0];
            float4 a1 = x[i1];
            float4 a2 = x[i2];
            float4 a3 = x[i3];
            float4 b0 = t[i0];
            float4 b1 = t[i1];
            float4 b2 = t[i2];
            float4 b3 = t[i3];

            float d;
            d = a0.x - b0.x; acc0 = fmaf(d, d, acc0);
            d = a0.y - b0.y; acc0 = fmaf(d, d, acc0);
            d = a0.z - b0.z; acc0 = fmaf(d, d, acc0);
            d = a0.w - b0.w; acc0 = fmaf(d, d, acc0);

            d = a1.x - b1.x; acc1 = fmaf(d, d, acc1);
            d = a1.y - b1.y; acc1 = fmaf(d, d, acc1);
            d = a1.z - b1.z; acc1 = fmaf(d, d, acc1);
            d = a1.w - b1.w; acc1 = fmaf(d, d, acc1);

            d = a2.x - b2.x; acc2 = fmaf(d, d, acc2);
            d = a2.y - b2.y; acc2 = fmaf(d, d, acc2);
            d = a2.z - b2.z; acc2 = fmaf(d, d, acc2);
            d = a2.w - b2.w; acc2 = fmaf(d, d, acc2);

            d = a3.x - b3.x; acc3 = fmaf(d, d, acc3);
            d = a3.y - b3.y; acc3 = fmaf(d, d, acc3);
            d = a3.z - b3.z; acc3 = fmaf(d, d, acc3);
            d = a3.w - b3.w; acc3 = fmaf(d, d, acc3);
        }
    } else {
        // tail path (not taken for the bench shape)
        for (int k = 0; k < S1_ITERS; ++k) {
            const int i = base + k * S1_BLOCK;
            if (i < n4) {
                float4 a = x[i];
                float4 b = t[i];
                float d;
                d = a.x - b.x; acc0 = fmaf(d, d, acc0);
                d = a.y - b.y; acc1 = fmaf(d, d, acc1);
                d = a.z - b.z; acc2 = fmaf(d, d, acc2);
                d = a.w - b.w; acc3 = fmaf(d, d, acc3);
            }
        }
    }

    float acc = (acc0 + acc1) + (acc2 + acc3);

    // wave (64-lane) shuffle reduction
    #pragma unroll
    for (int off = 32; off > 0; off >>= 1)
        acc += __shfl_down(acc, off, 64);

    __shared__ float wave_sums[4];
    const int wave = tid >> 6;
    const int lane = tid & 63;
    if (lane == 0) wave_sums[wave] = acc;
    __syncthreads();

    if (tid == 0)
        ws[blockIdx.x] = (wave_sums[0] + wave_sums[1]) + (wave_sums[2] + wave_sums[3]);
}

__global__ __launch_bounds__(256) void haar_mse_stage2(
    const float* __restrict__ ws,
    float* __restrict__ out,
    int nblocks,
    float scale)
{
    float s = 0.0f;
    for (int i = threadIdx.x; i < nblocks; i += 256)
        s += ws[i];

    #pragma unroll
    for (int off = 32; off > 0; off >>= 1)
        s += __shfl_down(s, off, 64);

    __shared__ float wave_sums[4];
    const int wave = threadIdx.x >> 6;
    const int lane = threadIdx.x & 63;
    if (lane == 0) wave_sums[wave] = s;
    __syncthreads();

    if (threadIdx.x == 0)
        out[0] = ((wave_sums[0] + wave_sums[1]) + (wave_sums[2] + wave_sums[3])) * scale;
}

extern "C" void kernel_launch(void* const* d_in, const int* in_sizes, int n_in,
                              void* d_out, int out_size, void* d_ws, size_t ws_size,
                              hipStream_t stream) {
    const float* x = (const float*)d_in[0];
    const float* t = (const float*)d_in[1];
    float* out = (float*)d_out;
    float* ws  = (float*)d_ws;

    const int n  = in_sizes[0];   // 33554432
    const int n4 = n / 4;         // 8388608 float4s
    const int nblocks = (n4 + S1_CHUNK - 1) / S1_CHUNK;   // 2048

    haar_mse_stage1<<<nblocks, S1_BLOCK, 0, stream>>>(
        (const float4*)x, (const float4*)t, ws, n4);

    const float scale = 1.0f / (float)(n / 4);            // 1/8388608
    haar_mse_stage2<<<1, 256, 0, stream>>>(ws, out, nblocks, scale);
}

// Round 5
// 253.627 us; speedup vs baseline: 1.1011x; 1.1011x over previous
//
#include <hip/hip_runtime.h>

// loss = sum((input - target)^2) / (N/4), by orthonormality of the 2x2 Haar
// transform (sum of the 4 band MSEs == overall pixel SSE * 4/N).
// N = 4*32*512*512 = 33554432; divisor = N/4 = 8388608.
//
// Stage 1: 8192 blocks (4 refill rounds per CU residency slot -> dynamic
//          load balance; R3's exact-fill 2048 blocks showed 31% avg occupancy
//          from stragglers). Each block: contiguous 1024-float4 chunk per
//          tensor, 4 float4s per thread per tensor, NONTEMPORAL loads (data
//          is read once -> bypass cache allocation, stream at HBM rate).
// Stage 2: one block sums the 8192 partials, writes the scaled scalar.

// native vector type — __builtin_nontemporal_load requires a native vector,
// not HIP's float4 class.
typedef float fvec4 __attribute__((ext_vector_type(4)));

#define S1_BLOCK 256
#define S1_ITERS 4                       // float4s per thread per tensor
#define S1_CHUNK (S1_BLOCK * S1_ITERS)   // 1024 float4s per block

__global__ __launch_bounds__(S1_BLOCK) void haar_mse_stage1(
    const fvec4* __restrict__ x,
    const fvec4* __restrict__ t,
    float* __restrict__ ws,
    int n4)
{
    const int tid  = threadIdx.x;
    const int base = blockIdx.x * S1_CHUNK + tid;

    float acc0 = 0.0f, acc1 = 0.0f, acc2 = 0.0f, acc3 = 0.0f;

    if (base + 3 * S1_BLOCK < n4) {
        // fast path (always taken for the bench shape): 8 nt loads in flight
        fvec4 a0 = __builtin_nontemporal_load(&x[base]);
        fvec4 a1 = __builtin_nontemporal_load(&x[base + S1_BLOCK]);
        fvec4 a2 = __builtin_nontemporal_load(&x[base + 2 * S1_BLOCK]);
        fvec4 a3 = __builtin_nontemporal_load(&x[base + 3 * S1_BLOCK]);
        fvec4 b0 = __builtin_nontemporal_load(&t[base]);
        fvec4 b1 = __builtin_nontemporal_load(&t[base + S1_BLOCK]);
        fvec4 b2 = __builtin_nontemporal_load(&t[base + 2 * S1_BLOCK]);
        fvec4 b3 = __builtin_nontemporal_load(&t[base + 3 * S1_BLOCK]);

        fvec4 d0 = a0 - b0;
        fvec4 d1 = a1 - b1;
        fvec4 d2 = a2 - b2;
        fvec4 d3 = a3 - b3;

        acc0 = fmaf(d0.x, d0.x, acc0);
        acc0 = fmaf(d0.y, d0.y, acc0);
        acc0 = fmaf(d0.z, d0.z, acc0);
        acc0 = fmaf(d0.w, d0.w, acc0);

        acc1 = fmaf(d1.x, d1.x, acc1);
        acc1 = fmaf(d1.y, d1.y, acc1);
        acc1 = fmaf(d1.z, d1.z, acc1);
        acc1 = fmaf(d1.w, d1.w, acc1);

        acc2 = fmaf(d2.x, d2.x, acc2);
        acc2 = fmaf(d2.y, d2.y, acc2);
        acc2 = fmaf(d2.z, d2.z, acc2);
        acc2 = fmaf(d2.w, d2.w, acc2);

        acc3 = fmaf(d3.x, d3.x, acc3);
        acc3 = fmaf(d3.y, d3.y, acc3);
        acc3 = fmaf(d3.z, d3.z, acc3);
        acc3 = fmaf(d3.w, d3.w, acc3);
    } else {
        // tail path (not taken for the bench shape)
        for (int k = 0; k < S1_ITERS; ++k) {
            const int i = base + k * S1_BLOCK;
            if (i < n4) {
                fvec4 a = x[i];
                fvec4 b = t[i];
                fvec4 d = a - b;
                acc0 = fmaf(d.x, d.x, acc0);
                acc1 = fmaf(d.y, d.y, acc1);
                acc2 = fmaf(d.z, d.z, acc2);
                acc3 = fmaf(d.w, d.w, acc3);
            }
        }
    }

    float acc = (acc0 + acc1) + (acc2 + acc3);

    // wave (64-lane) shuffle reduction
    #pragma unroll
    for (int off = 32; off > 0; off >>= 1)
        acc += __shfl_down(acc, off, 64);

    __shared__ float wave_sums[4];
    const int wave = tid >> 6;
    const int lane = tid & 63;
    if (lane == 0) wave_sums[wave] = acc;
    __syncthreads();

    if (tid == 0)
        ws[blockIdx.x] = (wave_sums[0] + wave_sums[1]) + (wave_sums[2] + wave_sums[3]);
}

__global__ __launch_bounds__(256) void haar_mse_stage2(
    const float* __restrict__ ws,
    float* __restrict__ out,
    int nblocks,
    float scale)
{
    float s = 0.0f;
    for (int i = threadIdx.x; i < nblocks; i += 256)
        s += ws[i];

    #pragma unroll
    for (int off = 32; off > 0; off >>= 1)
        s += __shfl_down(s, off, 64);

    __shared__ float wave_sums[4];
    const int wave = threadIdx.x >> 6;
    const int lane = threadIdx.x & 63;
    if (lane == 0) wave_sums[wave] = s;
    __syncthreads();

    if (threadIdx.x == 0)
        out[0] = ((wave_sums[0] + wave_sums[1]) + (wave_sums[2] + wave_sums[3])) * scale;
}

extern "C" void kernel_launch(void* const* d_in, const int* in_sizes, int n_in,
                              void* d_out, int out_size, void* d_ws, size_t ws_size,
                              hipStream_t stream) {
    const float* x = (const float*)d_in[0];
    const float* t = (const float*)d_in[1];
    float* out = (float*)d_out;
    float* ws  = (float*)d_ws;

    const int n  = in_sizes[0];   // 33554432
    const int n4 = n / 4;         // 8388608 float4s
    const int nblocks = (n4 + S1_CHUNK - 1) / S1_CHUNK;   // 8192

    haar_mse_stage1<<<nblocks, S1_BLOCK, 0, stream>>>(
        (const fvec4*)x, (const fvec4*)t, ws, n4);

    const float scale = 1.0f / (float)(n / 4);            // 1/8388608
    haar_mse_stage2<<<1, 256, 0, stream>>>(ws, out, nblocks, scale);
}

// Round 6
// 250.020 us; speedup vs baseline: 1.1170x; 1.0144x over previous
//
#include <hip/hip_runtime.h>

// loss = sum((input - target)^2) / (N/4), by orthonormality of the 2x2 Haar
// transform (sum of the 4 band MSEs == overall pixel SSE * 4/N).
// N = 4*32*512*512 = 33554432; divisor = N/4 = 8388608.
//
// Harness floor discovered in R5: ~170 us of dur_us is the harness's own
// d_ws 512MB 0xAA fill (77 us @ 6.9 TB/s) + d_in restore — untouchable.
// Controllable part = stage1 (+ tiny stage2). Stage1 strategy: nontemporal
// streaming loads (read-once data), deep MLP (16 loads in flight/thread),
// contiguous per-block chunks, 4096 blocks (2 refill rounds/CU).

typedef float fvec4 __attribute__((ext_vector_type(4)));

#define S1_BLOCK 256
#define S1_ITERS 8                       // float4s per thread per tensor
#define S1_CHUNK (S1_BLOCK * S1_ITERS)   // 2048 float4s per block

__global__ __launch_bounds__(S1_BLOCK) void haar_mse_stage1(
    const fvec4* __restrict__ x,
    const fvec4* __restrict__ t,
    float* __restrict__ ws,
    int n4)
{
    const int tid  = threadIdx.x;
    const int base = blockIdx.x * S1_CHUNK + tid;

    float acc0 = 0.0f, acc1 = 0.0f, acc2 = 0.0f, acc3 = 0.0f;

    if (base + (S1_ITERS - 1) * S1_BLOCK < n4) {
        // fast path (always taken for the bench shape): 16 nt loads in flight
        fvec4 a[S1_ITERS], b[S1_ITERS];
        #pragma unroll
        for (int k = 0; k < S1_ITERS; ++k)
            a[k] = __builtin_nontemporal_load(&x[base + k * S1_BLOCK]);
        #pragma unroll
        for (int k = 0; k < S1_ITERS; ++k)
            b[k] = __builtin_nontemporal_load(&t[base + k * S1_BLOCK]);

        #pragma unroll
        for (int k = 0; k < S1_ITERS; ++k) {
            fvec4 d = a[k] - b[k];
            acc0 = fmaf(d.x, d.x, acc0);
            acc1 = fmaf(d.y, d.y, acc1);
            acc2 = fmaf(d.z, d.z, acc2);
            acc3 = fmaf(d.w, d.w, acc3);
        }
    } else {
        // tail path (not taken for the bench shape)
        for (int k = 0; k < S1_ITERS; ++k) {
            const int i = base + k * S1_BLOCK;
            if (i < n4) {
                fvec4 a = x[i];
                fvec4 b = t[i];
                fvec4 d = a - b;
                acc0 = fmaf(d.x, d.x, acc0);
                acc1 = fmaf(d.y, d.y, acc1);
                acc2 = fmaf(d.z, d.z, acc2);
                acc3 = fmaf(d.w, d.w, acc3);
            }
        }
    }

    float acc = (acc0 + acc1) + (acc2 + acc3);

    // wave (64-lane) shuffle reduction
    #pragma unroll
    for (int off = 32; off > 0; off >>= 1)
        acc += __shfl_down(acc, off, 64);

    __shared__ float wave_sums[4];
    const int wave = tid >> 6;
    const int lane = tid & 63;
    if (lane == 0) wave_sums[wave] = acc;
    __syncthreads();

    if (tid == 0)
        ws[blockIdx.x] = (wave_sums[0] + wave_sums[1]) + (wave_sums[2] + wave_sums[3]);
}

__global__ __launch_bounds__(256) void haar_mse_stage2(
    const float* __restrict__ ws,
    float* __restrict__ out,
    int nblocks,
    float scale)
{
    float s = 0.0f;
    for (int i = threadIdx.x; i < nblocks; i += 256)
        s += ws[i];

    #pragma unroll
    for (int off = 32; off > 0; off >>= 1)
        s += __shfl_down(s, off, 64);

    __shared__ float wave_sums[4];
    const int wave = threadIdx.x >> 6;
    const int lane = threadIdx.x & 63;
    if (lane == 0) wave_sums[wave] = s;
    __syncthreads();

    if (threadIdx.x == 0)
        out[0] = ((wave_sums[0] + wave_sums[1]) + (wave_sums[2] + wave_sums[3])) * scale;
}

extern "C" void kernel_launch(void* const* d_in, const int* in_sizes, int n_in,
                              void* d_out, int out_size, void* d_ws, size_t ws_size,
                              hipStream_t stream) {
    const float* x = (const float*)d_in[0];
    const float* t = (const float*)d_in[1];
    float* out = (float*)d_out;
    float* ws  = (float*)d_ws;

    const int n  = in_sizes[0];   // 33554432
    const int n4 = n / 4;         // 8388608 float4s
    const int nblocks = (n4 + S1_CHUNK - 1) / S1_CHUNK;   // 4096

    haar_mse_stage1<<<nblocks, S1_BLOCK, 0, stream>>>(
        (const fvec4*)x, (const fvec4*)t, ws, n4);

    const float scale = 1.0f / (float)(n / 4);            // 1/8388608
    haar_mse_stage2<<<1, 256, 0, stream>>>(ws, out, nblocks, scale);
}